// Round 4
// baseline (713.395 us; speedup 1.0000x reference)
//
#include <hip/hip_runtime.h>
#include <hip/hip_bf16.h>
#include <math.h>

// Bahdanau attention + reservoir RNN cell.
//  K0: Ua_w f32 -> bf16 in MFMA B-fragment layout (L2-resident, read direct)
//  K1: q = h_prev@Wa^T + Wa_b + Ua_b
//  K2: per (b, 64-row chunk): bf16 MFMA GEMM. A: full 64KB LDS tile, 4 kc
//      phases, T14 issue-early/write-late staging. B: fragment-layout from L2
//      with DEPTH-1 REGISTER DOUBLE-BUFFER (bA/bB) so each 4-load L2 batch
//      hides under the previous 16-MFMA cluster. Epilogue: tanh(q+k)·Va ->
//      partial softmax (m,l) + partial context from the bf16 LDS tile.
//  K3: exact combine of 32 partials -> context
//  K4: RNN cell (grid split over o for full-chip coverage)

typedef __attribute__((ext_vector_type(8))) short short8;
typedef __attribute__((ext_vector_type(8))) unsigned short ushort8;
typedef __attribute__((ext_vector_type(4))) float f32x4;

#define S_LEN 2048
#define BDIM 128
#define HDIM 512
#define EDIM 512
#define BM 64
#define BK 128
#define NK (HDIM / BK)       // 4
#define NCHUNK (S_LEN / BM)  // 32

__device__ __forceinline__ unsigned short f2bf(float f) {
  unsigned int u = __float_as_uint(f);
  u += 0x7fffu + ((u >> 16) & 1u);  // RNE
  return (unsigned short)(u >> 16);
}

__device__ __forceinline__ float bf2f(unsigned short u) {
  return __uint_as_float(((unsigned int)u) << 16);
}

__device__ __forceinline__ float fast_tanh(float x) {
  float e = __expf(2.0f * x);
  return 1.0f - 2.0f / (e + 1.0f);
}

// Ua[512][512] f32 -> bf16 fragment layout:
// tile (ct,kt): col = ct*16 + (l&15), k = kt*32 + (l>>4)*8 + e
// at dst[((ct*16+kt)*64 + l)*8 + e]
__global__ __launch_bounds__(256) void k_cvt_b(const float* __restrict__ src,
                                               unsigned short* __restrict__ dst) {
  int tid = blockIdx.x * 256 + threadIdx.x;  // 0..32767
  int ct = tid >> 10;
  int kt = (tid >> 6) & 15;
  int l = tid & 63;
  int col = ct * 16 + (l & 15);
  int k = kt * 32 + (l >> 4) * 8;
  const float4* s = (const float4*)(src + (size_t)col * HDIM + k);
  float4 v0 = s[0], v1 = s[1];
  ushort8 p;
  p[0] = f2bf(v0.x); p[1] = f2bf(v0.y); p[2] = f2bf(v0.z); p[3] = f2bf(v0.w);
  p[4] = f2bf(v1.x); p[5] = f2bf(v1.y); p[6] = f2bf(v1.z); p[7] = f2bf(v1.w);
  *(ushort8*)(dst + (size_t)tid * 8) = p;
}

__global__ __launch_bounds__(256) void k_q(const float* __restrict__ hp,
                                           const float* __restrict__ Wa,
                                           const float* __restrict__ Wab,
                                           const float* __restrict__ Uab,
                                           float* __restrict__ q) {
  int b = blockIdx.x, oh = blockIdx.y;
  int o = oh * 256 + threadIdx.x;
  __shared__ float hs[HDIM];
  hs[threadIdx.x] = hp[b * HDIM + threadIdx.x];
  hs[threadIdx.x + 256] = hp[b * HDIM + threadIdx.x + 256];
  __syncthreads();
  const float4* wr = (const float4*)(Wa + (size_t)o * HDIM);
  float acc = 0.f;
#pragma unroll 8
  for (int i = 0; i < HDIM / 4; ++i) {
    float4 v = wr[i];
    acc += v.x * hs[i * 4 + 0] + v.y * hs[i * 4 + 1] + v.z * hs[i * 4 + 2] + v.w * hs[i * 4 + 3];
  }
  q[b * HDIM + o] = acc + Wab[o] + Uab[o];
}

__global__ __launch_bounds__(512, 4) void k_scores_ctx(
    const float* __restrict__ xref, const unsigned short* __restrict__ uab,
    const float* __restrict__ q, const float* __restrict__ va,
    float* __restrict__ mArr, float* __restrict__ lArr, float* __restrict__ cpart) {
  int chunk = blockIdx.x;
  int b = blockIdx.y;
  int tid = threadIdx.x;
  int l = tid & 63;
  int w = tid >> 6;   // 0..7, wave owns 64 output cols
  int q4 = l >> 4;

  __shared__ __align__(16) unsigned short As[BM * HDIM];  // 64 KB, swizzled bf16
  __shared__ float sc[BM];
  __shared__ float pl[BM];
  if (tid < BM) sc[tid] = 0.f;

  f32x4 acc[4][4];
#pragma unroll
  for (int m = 0; m < 4; ++m)
#pragma unroll
    for (int n = 0; n < 4; ++n) acc[m][n] = f32x4{0.f, 0.f, 0.f, 0.f};

  const float* xb = xref + ((size_t)b * S_LEN + (size_t)chunk * BM) * HDIM;

  // staging: 8 threads per row; thread covers k-slots skq and skq+8 of the kc tile
  int srow = tid >> 3, skq = tid & 7;
  int slotA = skq ^ (srow & 7);
  const float* sbase = xb + (size_t)srow * HDIM + (size_t)skq * 8;

  float4 xa0, xa1, xb0, xb1;
  short8 bA[4], bB[4];

#define LOADKC(kc)                                      \
  {                                                     \
    const float* bp = sbase + (kc) * BK;                \
    xa0 = ((const float4*)bp)[0];                       \
    xa1 = ((const float4*)bp)[1];                       \
    xb0 = ((const float4*)(bp + 64))[0];                \
    xb1 = ((const float4*)(bp + 64))[1];                \
  }

#define WRITEKC(kc)                                                    \
  {                                                                    \
    ushort8 pA, pB;                                                    \
    pA[0] = f2bf(xa0.x); pA[1] = f2bf(xa0.y); pA[2] = f2bf(xa0.z);     \
    pA[3] = f2bf(xa0.w); pA[4] = f2bf(xa1.x); pA[5] = f2bf(xa1.y);     \
    pA[6] = f2bf(xa1.z); pA[7] = f2bf(xa1.w);                          \
    pB[0] = f2bf(xb0.x); pB[1] = f2bf(xb0.y); pB[2] = f2bf(xb0.z);     \
    pB[3] = f2bf(xb0.w); pB[4] = f2bf(xb1.x); pB[5] = f2bf(xb1.y);     \
    pB[6] = f2bf(xb1.z); pB[7] = f2bf(xb1.w);                          \
    int base = srow * HDIM + (kc) * BK + slotA * 8;                    \
    *(ushort8*)&As[base] = pA;                                         \
    *(ushort8*)&As[base + 64] = pB;                                    \
  }

  // load B fragments for k-tile kt (4 cols groups of this wave) into dst regs
#define LOADB(dst, kt)                                                        \
  {                                                                           \
    _Pragma("unroll")                                                         \
    for (int n = 0; n < 4; ++n)                                               \
      dst[n] = *(const short8*)(uab +                                         \
               (((size_t)((w * 4 + n) * 16 + (kt)) * 64 + l) * 8));           \
  }

  // 16-MFMA cluster on k-tile (kc,kk) consuming register B set `breg`
#define CLUSTER(breg, kc, kk)                                                 \
  {                                                                           \
    short8 afr[4];                                                            \
    int j = (kk) * 4 + q4;                                                    \
    _Pragma("unroll")                                                         \
    for (int m = 0; m < 4; ++m) {                                             \
      int row = m * 16 + (l & 15);                                            \
      int P = (j & 8) | ((j & 7) ^ (row & 7));                                \
      afr[m] = *(const short8*)&As[row * HDIM + (kc) * BK + P * 8];           \
    }                                                                         \
    __builtin_amdgcn_s_setprio(1);                                            \
    _Pragma("unroll")                                                         \
    for (int m = 0; m < 4; ++m)                                               \
      _Pragma("unroll")                                                       \
      for (int n = 0; n < 4; ++n)                                             \
        acc[m][n] = __builtin_amdgcn_mfma_f32_16x16x32_bf16(afr[m], breg[n],  \
                                                            acc[m][n], 0, 0, 0); \
    __builtin_amdgcn_s_setprio(0);                                            \
  }

  LOADKC(0);
  LOADB(bA, 0);
  WRITEKC(0);
  __syncthreads();

  // kc = 0 (kt 0..3)
  LOADKC(1);
  LOADB(bB, 1);  CLUSTER(bA, 0, 0);
  LOADB(bA, 2);  CLUSTER(bB, 0, 1);
  LOADB(bB, 3);  CLUSTER(bA, 0, 2);
  LOADB(bA, 4);  CLUSTER(bB, 0, 3);
  WRITEKC(1);
  __syncthreads();

  // kc = 1 (kt 4..7)
  LOADKC(2);
  LOADB(bB, 5);  CLUSTER(bA, 1, 0);
  LOADB(bA, 6);  CLUSTER(bB, 1, 1);
  LOADB(bB, 7);  CLUSTER(bA, 1, 2);
  LOADB(bA, 8);  CLUSTER(bB, 1, 3);
  WRITEKC(2);
  __syncthreads();

  // kc = 2 (kt 8..11)
  LOADKC(3);
  LOADB(bB, 9);  CLUSTER(bA, 2, 0);
  LOADB(bA, 10); CLUSTER(bB, 2, 1);
  LOADB(bB, 11); CLUSTER(bA, 2, 2);
  LOADB(bA, 12); CLUSTER(bB, 2, 3);
  WRITEKC(3);
  __syncthreads();

  // kc = 3 (kt 12..15); hoist q/Va loads under the first clusters
  int c = l & 15, g4 = l >> 4;
  float qf[4], vf[4];
#pragma unroll
  for (int n = 0; n < 4; ++n) {
    int o = w * 64 + n * 16 + c;
    qf[n] = q[b * HDIM + o];
    vf[n] = va[o];
  }
  LOADB(bB, 13); CLUSTER(bA, 3, 0);
  LOADB(bA, 14); CLUSTER(bB, 3, 1);
  LOADB(bB, 15); CLUSTER(bA, 3, 2);
                 CLUSTER(bB, 3, 3);

  // scores[row] = sum_o tanh(acc + q[o]) * Va[o]
#pragma unroll
  for (int m = 0; m < 4; ++m) {
#pragma unroll
    for (int r = 0; r < 4; ++r) {
      float sum = 0.f;
#pragma unroll
      for (int n = 0; n < 4; ++n) sum += fast_tanh(acc[m][n][r] + qf[n]) * vf[n];
      sum += __shfl_xor(sum, 1);
      sum += __shfl_xor(sum, 2);
      sum += __shfl_xor(sum, 4);
      sum += __shfl_xor(sum, 8);
      if (c == 0) atomicAdd(&sc[m * 16 + g4 * 4 + r], sum);
    }
  }
  __syncthreads();

  // partial softmax over the 64 local rows
  float M = sc[l];
#pragma unroll
  for (int off = 32; off >= 1; off >>= 1) M = fmaxf(M, __shfl_xor(M, off));
  float p = __expf(sc[l] - M);
  float lsum = p;
#pragma unroll
  for (int off = 32; off >= 1; off >>= 1) lsum += __shfl_xor(lsum, off);
  if (tid < BM) pl[tid] = p;
  if (tid == 0) {
    mArr[b * NCHUNK + chunk] = M;
    lArr[b * NCHUNK + chunk] = lsum;
  }
  __syncthreads();

  // partial context from the bf16 LDS tile (no global re-read)
  {
    int kc_t = tid >> 7;
    int jj = (tid >> 3) & 15;
    int e = tid & 7;
    int base = kc_t * BK + (jj & 8) * 8 + e;  // (j&8) part of P is row-independent
    int jl = jj & 7;
    float cacc = 0.f;
#pragma unroll 8
    for (int r = 0; r < BM; ++r) {
      int P_low = jl ^ (r & 7);
      cacc += pl[r] * bf2f(As[r * HDIM + base + P_low * 8]);
    }
    cpart[((size_t)b * NCHUNK + chunk) * HDIM + tid] = cacc;
  }
#undef LOADKC
#undef WRITEKC
#undef LOADB
#undef CLUSTER
}

__global__ __launch_bounds__(512) void k_combine(const float* __restrict__ mArr,
                                                 const float* __restrict__ lArr,
                                                 const float* __restrict__ cpart,
                                                 float* __restrict__ ctx,
                                                 float* __restrict__ out_ctx) {
  int b = blockIdx.x, t = threadIdx.x;
  __shared__ float wf[NCHUNK];
  __shared__ float dinv;
  if (t == 0) {
    float M = mArr[b * NCHUNK];
    for (int i = 1; i < NCHUNK; ++i) M = fmaxf(M, mArr[b * NCHUNK + i]);
    float den = 0.f;
    for (int i = 0; i < NCHUNK; ++i) {
      float f = __expf(mArr[b * NCHUNK + i] - M);
      wf[i] = f;
      den += f * lArr[b * NCHUNK + i];
    }
    dinv = 1.0f / den;
  }
  __syncthreads();
  float s = 0.f;
#pragma unroll
  for (int i = 0; i < NCHUNK; ++i) s += wf[i] * cpart[((size_t)b * NCHUNK + i) * HDIM + t];
  float c = s * dinv;
  ctx[b * HDIM + t] = c;
  out_ctx[b * HDIM + t] = c;
}

__global__ __launch_bounds__(256) void k_rnn(const float* __restrict__ xt,
                                             const float* __restrict__ ctx,
                                             const float* __restrict__ hp,
                                             const float* __restrict__ Wih,
                                             const float* __restrict__ Wihb,
                                             const float* __restrict__ Whh,
                                             const float* __restrict__ Whhb,
                                             float* __restrict__ hout) {
  int b = blockIdx.x, oh = blockIdx.y;
  int o = oh * 256 + threadIdx.x;
  __shared__ float xs[EDIM], cs[HDIM], hs[HDIM];
  xs[threadIdx.x] = xt[b * EDIM + threadIdx.x];
  xs[threadIdx.x + 256] = xt[b * EDIM + threadIdx.x + 256];
  cs[threadIdx.x] = ctx[b * HDIM + threadIdx.x];
  cs[threadIdx.x + 256] = ctx[b * HDIM + threadIdx.x + 256];
  hs[threadIdx.x] = hp[b * HDIM + threadIdx.x];
  hs[threadIdx.x + 256] = hp[b * HDIM + threadIdx.x + 256];
  __syncthreads();
  const float4* wi = (const float4*)(Wih + (size_t)o * (EDIM + HDIM));
  float acc = Wihb[o] + Whhb[o];
#pragma unroll 8
  for (int i = 0; i < EDIM / 4; ++i) {
    float4 v = wi[i];
    acc += v.x * xs[i * 4] + v.y * xs[i * 4 + 1] + v.z * xs[i * 4 + 2] + v.w * xs[i * 4 + 3];
  }
  const float4* wi2 = wi + EDIM / 4;
#pragma unroll 8
  for (int i = 0; i < HDIM / 4; ++i) {
    float4 v = wi2[i];
    acc += v.x * cs[i * 4] + v.y * cs[i * 4 + 1] + v.z * cs[i * 4 + 2] + v.w * cs[i * 4 + 3];
  }
  const float4* wh = (const float4*)(Whh + (size_t)o * HDIM);
#pragma unroll 8
  for (int i = 0; i < HDIM / 4; ++i) {
    float4 v = wh[i];
    acc += v.x * hs[i * 4] + v.y * hs[i * 4 + 1] + v.z * hs[i * 4 + 2] + v.w * hs[i * 4 + 3];
  }
  hout[b * HDIM + o] = tanhf(acc);
}

extern "C" void kernel_launch(void* const* d_in, const int* in_sizes, int n_in,
                              void* d_out, int out_size, void* d_ws, size_t ws_size,
                              hipStream_t stream) {
  const float* x_t    = (const float*)d_in[0];
  const float* x_ref  = (const float*)d_in[1];
  const float* h_prev = (const float*)d_in[2];
  const float* Wa_w   = (const float*)d_in[3];
  const float* Wa_b   = (const float*)d_in[4];
  const float* Ua_w   = (const float*)d_in[5];
  const float* Ua_b   = (const float*)d_in[6];
  const float* Va_w   = (const float*)d_in[7];
  // d_in[8] = Va_b: softmax-invariant, skipped.
  const float* Wih_w  = (const float*)d_in[9];
  const float* Wih_b  = (const float*)d_in[10];
  const float* Whh_w  = (const float*)d_in[11];
  const float* Whh_b  = (const float*)d_in[12];

  char* ws = (char*)d_ws;
  unsigned short* ua_fr = (unsigned short*)ws;   // 512 KB fragment-layout Ua
  float* q     = (float*)(ws + 524288);          // 256 KB
  float* mArr  = (float*)(ws + 786432);          // 16 KB
  float* lArr  = (float*)(ws + 802816);          // 16 KB
  float* cpart = (float*)(ws + 819200);          // 8 MB
  float* ctx   = (float*)(ws + 9207808);         // 256 KB

  float* h_out   = (float*)d_out;
  float* ctx_out = h_out + BDIM * HDIM;

  k_cvt_b<<<dim3(128), dim3(256), 0, stream>>>(Ua_w, ua_fr);
  k_q<<<dim3(BDIM, 2), dim3(256), 0, stream>>>(h_prev, Wa_w, Wa_b, Ua_b, q);
  k_scores_ctx<<<dim3(NCHUNK, BDIM), dim3(512), 0, stream>>>(x_ref, ua_fr, q, Va_w, mArr, lArr, cpart);
  k_combine<<<dim3(BDIM), dim3(512), 0, stream>>>(mArr, lArr, cpart, ctx, ctx_out);
  k_rnn<<<dim3(BDIM, 2), dim3(256), 0, stream>>>(x_t, ctx, h_prev, Wih_w, Wih_b, Whh_w, Whh_b, h_out);
}

// Round 5
// 376.808 us; speedup vs baseline: 1.8933x; 1.8933x over previous
//
#include <hip/hip_runtime.h>
#include <hip/hip_bf16.h>
#include <math.h>

// Bahdanau attention + reservoir RNN cell.
//  K0: Ua_w f32 -> bf16 in MFMA B-fragment layout (L2-resident, read direct)
//  K1: q = h_prev@Wa^T + Wa_b + Ua_b
//  K2: per (b, 64-row chunk): bf16 MFMA GEMM. A: full 64KB LDS tile, 4 kc
//      phases, T14 issue-early/write-late staging. B: fragment-layout from L2.
//      Epilogue: tanh(q+k)·Va -> partial softmax (m,l) + partial context from
//      the bf16 LDS tile.
//      NOTE: plain __launch_bounds__(512) — the (512,4) variant forced a
//      64-VGPR budget and ~243 MB/dispatch of scratch spill (rocprof R3/R4).
//  K3: exact combine of 32 partials -> context
//  K4: RNN cell (grid split over o for full-chip coverage)

typedef __attribute__((ext_vector_type(8))) short short8;
typedef __attribute__((ext_vector_type(8))) unsigned short ushort8;
typedef __attribute__((ext_vector_type(4))) float f32x4;

#define S_LEN 2048
#define BDIM 128
#define HDIM 512
#define EDIM 512
#define BM 64
#define BK 128
#define NK (HDIM / BK)       // 4
#define NCHUNK (S_LEN / BM)  // 32

__device__ __forceinline__ unsigned short f2bf(float f) {
  unsigned int u = __float_as_uint(f);
  u += 0x7fffu + ((u >> 16) & 1u);  // RNE
  return (unsigned short)(u >> 16);
}

__device__ __forceinline__ float bf2f(unsigned short u) {
  return __uint_as_float(((unsigned int)u) << 16);
}

__device__ __forceinline__ float fast_tanh(float x) {
  float e = __expf(2.0f * x);
  return 1.0f - 2.0f / (e + 1.0f);
}

// Ua[512][512] f32 -> bf16 fragment layout:
// tile (ct,kt): col = ct*16 + (l&15), k = kt*32 + (l>>4)*8 + e
// at dst[((ct*16+kt)*64 + l)*8 + e]
__global__ __launch_bounds__(256) void k_cvt_b(const float* __restrict__ src,
                                               unsigned short* __restrict__ dst) {
  int tid = blockIdx.x * 256 + threadIdx.x;  // 0..32767
  int ct = tid >> 10;
  int kt = (tid >> 6) & 15;
  int l = tid & 63;
  int col = ct * 16 + (l & 15);
  int k = kt * 32 + (l >> 4) * 8;
  const float4* s = (const float4*)(src + (size_t)col * HDIM + k);
  float4 v0 = s[0], v1 = s[1];
  ushort8 p;
  p[0] = f2bf(v0.x); p[1] = f2bf(v0.y); p[2] = f2bf(v0.z); p[3] = f2bf(v0.w);
  p[4] = f2bf(v1.x); p[5] = f2bf(v1.y); p[6] = f2bf(v1.z); p[7] = f2bf(v1.w);
  *(ushort8*)(dst + (size_t)tid * 8) = p;
}

__global__ __launch_bounds__(256) void k_q(const float* __restrict__ hp,
                                           const float* __restrict__ Wa,
                                           const float* __restrict__ Wab,
                                           const float* __restrict__ Uab,
                                           float* __restrict__ q) {
  int b = blockIdx.x, oh = blockIdx.y;
  int o = oh * 256 + threadIdx.x;
  __shared__ float hs[HDIM];
  hs[threadIdx.x] = hp[b * HDIM + threadIdx.x];
  hs[threadIdx.x + 256] = hp[b * HDIM + threadIdx.x + 256];
  __syncthreads();
  const float4* wr = (const float4*)(Wa + (size_t)o * HDIM);
  float acc = 0.f;
#pragma unroll 8
  for (int i = 0; i < HDIM / 4; ++i) {
    float4 v = wr[i];
    acc += v.x * hs[i * 4 + 0] + v.y * hs[i * 4 + 1] + v.z * hs[i * 4 + 2] + v.w * hs[i * 4 + 3];
  }
  q[b * HDIM + o] = acc + Wab[o] + Uab[o];
}

__global__ __launch_bounds__(512) void k_scores_ctx(
    const float* __restrict__ xref, const unsigned short* __restrict__ uab,
    const float* __restrict__ q, const float* __restrict__ va,
    float* __restrict__ mArr, float* __restrict__ lArr, float* __restrict__ cpart) {
  int chunk = blockIdx.x;
  int b = blockIdx.y;
  int tid = threadIdx.x;
  int l = tid & 63;
  int w = tid >> 6;   // 0..7, wave owns 64 output cols
  int q4 = l >> 4;

  __shared__ __align__(16) unsigned short As[BM * HDIM];  // 64 KB, swizzled bf16
  __shared__ float sc[BM];
  __shared__ float pl[BM];
  if (tid < BM) sc[tid] = 0.f;

  f32x4 acc[4][4];
#pragma unroll
  for (int m = 0; m < 4; ++m)
#pragma unroll
    for (int n = 0; n < 4; ++n) acc[m][n] = f32x4{0.f, 0.f, 0.f, 0.f};

  const float* xb = xref + ((size_t)b * S_LEN + (size_t)chunk * BM) * HDIM;

  // staging: 8 threads per row; thread covers k-slots skq and skq+8 of the kc tile
  int srow = tid >> 3, skq = tid & 7;
  int slotA = skq ^ (srow & 7);
  const float* sbase = xb + (size_t)srow * HDIM + (size_t)skq * 8;

  float4 xa0, xa1, xb0, xb1;

#define LOADKC(kc)                                      \
  {                                                     \
    const float* bp = sbase + (kc) * BK;                \
    xa0 = ((const float4*)bp)[0];                       \
    xa1 = ((const float4*)bp)[1];                       \
    xb0 = ((const float4*)(bp + 64))[0];                \
    xb1 = ((const float4*)(bp + 64))[1];                \
  }

#define WRITEKC(kc)                                                    \
  {                                                                    \
    ushort8 pA, pB;                                                    \
    pA[0] = f2bf(xa0.x); pA[1] = f2bf(xa0.y); pA[2] = f2bf(xa0.z);     \
    pA[3] = f2bf(xa0.w); pA[4] = f2bf(xa1.x); pA[5] = f2bf(xa1.y);     \
    pA[6] = f2bf(xa1.z); pA[7] = f2bf(xa1.w);                          \
    pB[0] = f2bf(xb0.x); pB[1] = f2bf(xb0.y); pB[2] = f2bf(xb0.z);     \
    pB[3] = f2bf(xb0.w); pB[4] = f2bf(xb1.x); pB[5] = f2bf(xb1.y);     \
    pB[6] = f2bf(xb1.z); pB[7] = f2bf(xb1.w);                          \
    int base = srow * HDIM + (kc) * BK + slotA * 8;                    \
    *(ushort8*)&As[base] = pA;                                         \
    *(ushort8*)&As[base + 64] = pB;                                    \
  }

#define COMPUTEKC(kc)                                                          \
  {                                                                            \
    _Pragma("unroll")                                                          \
    for (int kk = 0; kk < 4; ++kk) {                                           \
      short8 afr[4], bfr[4];                                                   \
      int j = kk * 4 + q4;                                                     \
      _Pragma("unroll")                                                        \
      for (int m = 0; m < 4; ++m) {                                            \
        int row = m * 16 + (l & 15);                                           \
        int P = (j & 8) | ((j & 7) ^ (row & 7));                               \
        afr[m] = *(const short8*)&As[row * HDIM + (kc) * BK + P * 8];          \
      }                                                                        \
      _Pragma("unroll")                                                        \
      for (int n = 0; n < 4; ++n) {                                            \
        int ct = w * 4 + n, kt = (kc) * 4 + kk;                                \
        bfr[n] = *(const short8*)(uab + (((size_t)(ct * 16 + kt) * 64 + l) * 8)); \
      }                                                                        \
      __builtin_amdgcn_s_setprio(1);                                           \
      _Pragma("unroll")                                                        \
      for (int m = 0; m < 4; ++m)                                              \
        _Pragma("unroll")                                                      \
        for (int n = 0; n < 4; ++n)                                            \
          acc[m][n] = __builtin_amdgcn_mfma_f32_16x16x32_bf16(afr[m], bfr[n],  \
                                                              acc[m][n], 0, 0, 0); \
      __builtin_amdgcn_s_setprio(0);                                           \
    }                                                                          \
  }

  LOADKC(0);
  WRITEKC(0);
  __syncthreads();

  LOADKC(1);
  COMPUTEKC(0);
  WRITEKC(1);
  __syncthreads();

  LOADKC(2);
  COMPUTEKC(1);
  WRITEKC(2);
  __syncthreads();

  LOADKC(3);
  COMPUTEKC(2);
  WRITEKC(3);
  __syncthreads();

  // hoist q/Va loads under the last compute phase
  int c = l & 15, g4 = l >> 4;
  float qf[4], vf[4];
#pragma unroll
  for (int n = 0; n < 4; ++n) {
    int o = w * 64 + n * 16 + c;
    qf[n] = q[b * HDIM + o];
    vf[n] = va[o];
  }
  COMPUTEKC(3);

  // scores[row] = sum_o tanh(acc + q[o]) * Va[o]
#pragma unroll
  for (int m = 0; m < 4; ++m) {
#pragma unroll
    for (int r = 0; r < 4; ++r) {
      float sum = 0.f;
#pragma unroll
      for (int n = 0; n < 4; ++n) sum += fast_tanh(acc[m][n][r] + qf[n]) * vf[n];
      sum += __shfl_xor(sum, 1);
      sum += __shfl_xor(sum, 2);
      sum += __shfl_xor(sum, 4);
      sum += __shfl_xor(sum, 8);
      if (c == 0) atomicAdd(&sc[m * 16 + g4 * 4 + r], sum);
    }
  }
  __syncthreads();

  // partial softmax over the 64 local rows
  float M = sc[l];
#pragma unroll
  for (int off = 32; off >= 1; off >>= 1) M = fmaxf(M, __shfl_xor(M, off));
  float p = __expf(sc[l] - M);
  float lsum = p;
#pragma unroll
  for (int off = 32; off >= 1; off >>= 1) lsum += __shfl_xor(lsum, off);
  if (tid < BM) pl[tid] = p;
  if (tid == 0) {
    mArr[b * NCHUNK + chunk] = M;
    lArr[b * NCHUNK + chunk] = lsum;
  }
  __syncthreads();

  // partial context from the bf16 LDS tile (no global re-read)
  {
    int kc_t = tid >> 7;
    int jj = (tid >> 3) & 15;
    int e = tid & 7;
    int base = kc_t * BK + (jj & 8) * 8 + e;  // (j&8) part of P is row-independent
    int jl = jj & 7;
    float cacc = 0.f;
#pragma unroll 8
    for (int r = 0; r < BM; ++r) {
      int P_low = jl ^ (r & 7);
      cacc += pl[r] * bf2f(As[r * HDIM + base + P_low * 8]);
    }
    cpart[((size_t)b * NCHUNK + chunk) * HDIM + tid] = cacc;
  }
#undef LOADKC
#undef WRITEKC
#undef COMPUTEKC
}

__global__ __launch_bounds__(512) void k_combine(const float* __restrict__ mArr,
                                                 const float* __restrict__ lArr,
                                                 const float* __restrict__ cpart,
                                                 float* __restrict__ ctx,
                                                 float* __restrict__ out_ctx) {
  int b = blockIdx.x, t = threadIdx.x;
  __shared__ float wf[NCHUNK];
  __shared__ float dinv;
  if (t == 0) {
    float M = mArr[b * NCHUNK];
    for (int i = 1; i < NCHUNK; ++i) M = fmaxf(M, mArr[b * NCHUNK + i]);
    float den = 0.f;
    for (int i = 0; i < NCHUNK; ++i) {
      float f = __expf(mArr[b * NCHUNK + i] - M);
      wf[i] = f;
      den += f * lArr[b * NCHUNK + i];
    }
    dinv = 1.0f / den;
  }
  __syncthreads();
  float s = 0.f;
#pragma unroll
  for (int i = 0; i < NCHUNK; ++i) s += wf[i] * cpart[((size_t)b * NCHUNK + i) * HDIM + t];
  float c = s * dinv;
  ctx[b * HDIM + t] = c;
  out_ctx[b * HDIM + t] = c;
}

__global__ __launch_bounds__(256) void k_rnn(const float* __restrict__ xt,
                                             const float* __restrict__ ctx,
                                             const float* __restrict__ hp,
                                             const float* __restrict__ Wih,
                                             const float* __restrict__ Wihb,
                                             const float* __restrict__ Whh,
                                             const float* __restrict__ Whhb,
                                             float* __restrict__ hout) {
  int b = blockIdx.x, oh = blockIdx.y;
  int o = oh * 256 + threadIdx.x;
  __shared__ float xs[EDIM], cs[HDIM], hs[HDIM];
  xs[threadIdx.x] = xt[b * EDIM + threadIdx.x];
  xs[threadIdx.x + 256] = xt[b * EDIM + threadIdx.x + 256];
  cs[threadIdx.x] = ctx[b * HDIM + threadIdx.x];
  cs[threadIdx.x + 256] = ctx[b * HDIM + threadIdx.x + 256];
  hs[threadIdx.x] = hp[b * HDIM + threadIdx.x];
  hs[threadIdx.x + 256] = hp[b * HDIM + threadIdx.x + 256];
  __syncthreads();
  const float4* wi = (const float4*)(Wih + (size_t)o * (EDIM + HDIM));
  float acc = Wihb[o] + Whhb[o];
#pragma unroll 8
  for (int i = 0; i < EDIM / 4; ++i) {
    float4 v = wi[i];
    acc += v.x * xs[i * 4] + v.y * xs[i * 4 + 1] + v.z * xs[i * 4 + 2] + v.w * xs[i * 4 + 3];
  }
  const float4* wi2 = wi + EDIM / 4;
#pragma unroll 8
  for (int i = 0; i < HDIM / 4; ++i) {
    float4 v = wi2[i];
    acc += v.x * cs[i * 4] + v.y * cs[i * 4 + 1] + v.z * cs[i * 4 + 2] + v.w * cs[i * 4 + 3];
  }
  const float4* wh = (const float4*)(Whh + (size_t)o * HDIM);
#pragma unroll 8
  for (int i = 0; i < HDIM / 4; ++i) {
    float4 v = wh[i];
    acc += v.x * hs[i * 4] + v.y * hs[i * 4 + 1] + v.z * hs[i * 4 + 2] + v.w * hs[i * 4 + 3];
  }
  hout[b * HDIM + o] = tanhf(acc);
}

extern "C" void kernel_launch(void* const* d_in, const int* in_sizes, int n_in,
                              void* d_out, int out_size, void* d_ws, size_t ws_size,
                              hipStream_t stream) {
  const float* x_t    = (const float*)d_in[0];
  const float* x_ref  = (const float*)d_in[1];
  const float* h_prev = (const float*)d_in[2];
  const float* Wa_w   = (const float*)d_in[3];
  const float* Wa_b   = (const float*)d_in[4];
  const float* Ua_w   = (const float*)d_in[5];
  const float* Ua_b   = (const float*)d_in[6];
  const float* Va_w   = (const float*)d_in[7];
  // d_in[8] = Va_b: softmax-invariant, skipped.
  const float* Wih_w  = (const float*)d_in[9];
  const float* Wih_b  = (const float*)d_in[10];
  const float* Whh_w  = (const float*)d_in[11];
  const float* Whh_b  = (const float*)d_in[12];

  char* ws = (char*)d_ws;
  unsigned short* ua_fr = (unsigned short*)ws;   // 512 KB fragment-layout Ua
  float* q     = (float*)(ws + 524288);          // 256 KB
  float* mArr  = (float*)(ws + 786432);          // 16 KB
  float* lArr  = (float*)(ws + 802816);          // 16 KB
  float* cpart = (float*)(ws + 819200);          // 8 MB
  float* ctx   = (float*)(ws + 9207808);         // 256 KB

  float* h_out   = (float*)d_out;
  float* ctx_out = h_out + BDIM * HDIM;

  k_cvt_b<<<dim3(128), dim3(256), 0, stream>>>(Ua_w, ua_fr);
  k_q<<<dim3(BDIM, 2), dim3(256), 0, stream>>>(h_prev, Wa_w, Wa_b, Ua_b, q);
  k_scores_ctx<<<dim3(NCHUNK, BDIM), dim3(512), 0, stream>>>(x_ref, ua_fr, q, Va_w, mArr, lArr, cpart);
  k_combine<<<dim3(BDIM), dim3(512), 0, stream>>>(mArr, lArr, cpart, ctx, ctx_out);
  k_rnn<<<dim3(BDIM, 2), dim3(256), 0, stream>>>(x_t, ctx, h_prev, Wih_w, Wih_b, Whh_w, Whh_b, h_out);
}

// Round 6
// 362.417 us; speedup vs baseline: 1.9684x; 1.0397x over previous
//
#include <hip/hip_runtime.h>
#include <hip/hip_bf16.h>
#include <math.h>

// Bahdanau attention + reservoir RNN cell.
//  K0: Ua_w f32 -> bf16 in MFMA B-fragment layout (L2-resident, read direct)
//  K1: q = h_prev@Wa^T + Wa_b + Ua_b
//  K2: per (b, 128-row chunk): 1024-thread block, 16 waves (2 row-groups x 8
//      col-groups), acc 4x4 per wave (64 AGPR; total regs <=128 => 4 waves/SIMD).
//      A: full 128KB LDS tile, 4 kc phases, T14 issue-early/write-late staging.
//      B: fragment-layout direct from L2. Epilogue: tanh(q+k)·Va -> partial
//      softmax (m,l) + partial context from the bf16 LDS tile.
//  K3: exact combine of 16 partials -> context
//  K4: RNN cell (grid split over o for full-chip coverage)

typedef __attribute__((ext_vector_type(8))) short short8;
typedef __attribute__((ext_vector_type(8))) unsigned short ushort8;
typedef __attribute__((ext_vector_type(4))) float f32x4;

#define S_LEN 2048
#define BDIM 128
#define HDIM 512
#define EDIM 512
#define BM 128
#define BK 128
#define NK (HDIM / BK)       // 4
#define NCHUNK (S_LEN / BM)  // 16

__device__ __forceinline__ unsigned short f2bf(float f) {
  unsigned int u = __float_as_uint(f);
  u += 0x7fffu + ((u >> 16) & 1u);  // RNE
  return (unsigned short)(u >> 16);
}

__device__ __forceinline__ float bf2f(unsigned short u) {
  return __uint_as_float(((unsigned int)u) << 16);
}

__device__ __forceinline__ float fast_tanh(float x) {
  float e = __expf(2.0f * x);
  return 1.0f - 2.0f / (e + 1.0f);
}

// Ua[512][512] f32 -> bf16 fragment layout:
// tile (ct,kt): col = ct*16 + (l&15), k = kt*32 + (l>>4)*8 + e
// at dst[((ct*16+kt)*64 + l)*8 + e]
__global__ __launch_bounds__(256) void k_cvt_b(const float* __restrict__ src,
                                               unsigned short* __restrict__ dst) {
  int tid = blockIdx.x * 256 + threadIdx.x;  // 0..32767
  int ct = tid >> 10;
  int kt = (tid >> 6) & 15;
  int l = tid & 63;
  int col = ct * 16 + (l & 15);
  int k = kt * 32 + (l >> 4) * 8;
  const float4* s = (const float4*)(src + (size_t)col * HDIM + k);
  float4 v0 = s[0], v1 = s[1];
  ushort8 p;
  p[0] = f2bf(v0.x); p[1] = f2bf(v0.y); p[2] = f2bf(v0.z); p[3] = f2bf(v0.w);
  p[4] = f2bf(v1.x); p[5] = f2bf(v1.y); p[6] = f2bf(v1.z); p[7] = f2bf(v1.w);
  *(ushort8*)(dst + (size_t)tid * 8) = p;
}

__global__ __launch_bounds__(256) void k_q(const float* __restrict__ hp,
                                           const float* __restrict__ Wa,
                                           const float* __restrict__ Wab,
                                           const float* __restrict__ Uab,
                                           float* __restrict__ q) {
  int b = blockIdx.x, oh = blockIdx.y;
  int o = oh * 256 + threadIdx.x;
  __shared__ float hs[HDIM];
  hs[threadIdx.x] = hp[b * HDIM + threadIdx.x];
  hs[threadIdx.x + 256] = hp[b * HDIM + threadIdx.x + 256];
  __syncthreads();
  const float4* wr = (const float4*)(Wa + (size_t)o * HDIM);
  float acc = 0.f;
#pragma unroll 8
  for (int i = 0; i < HDIM / 4; ++i) {
    float4 v = wr[i];
    acc += v.x * hs[i * 4 + 0] + v.y * hs[i * 4 + 1] + v.z * hs[i * 4 + 2] + v.w * hs[i * 4 + 3];
  }
  q[b * HDIM + o] = acc + Wab[o] + Uab[o];
}

__global__ __launch_bounds__(1024) void k_scores_ctx(
    const float* __restrict__ xref, const unsigned short* __restrict__ uab,
    const float* __restrict__ q, const float* __restrict__ va,
    float* __restrict__ mArr, float* __restrict__ lArr, float* __restrict__ cpart) {
  int chunk = blockIdx.x;
  int b = blockIdx.y;
  int tid = threadIdx.x;
  int l = tid & 63;
  int w = tid >> 6;      // 0..15
  int wr = w >> 3;       // row-group 0/1 (64 rows each)
  int wc = w & 7;        // col-group 0..7 (64 cols each)
  int q4 = l >> 4;

  __shared__ __align__(16) unsigned short As[BM * HDIM];  // 128 KB, swizzled bf16
  __shared__ float sc[BM];
  __shared__ float pl[BM];
  __shared__ float s_ctx[HDIM];
  __shared__ float red1[16], bc[1], red2[2];

  if (tid < BM) sc[tid] = 0.f;

  f32x4 acc[4][4];
#pragma unroll
  for (int m = 0; m < 4; ++m)
#pragma unroll
    for (int n = 0; n < 4; ++n) acc[m][n] = f32x4{0.f, 0.f, 0.f, 0.f};

  const float* xb = xref + ((size_t)b * S_LEN + (size_t)chunk * BM) * HDIM;

  // staging: 8 threads per row (128 rows); thread covers k-slots skq, skq+8
  int srow = tid >> 3, skq = tid & 7;
  int slotA = skq ^ (srow & 7);
  const float* sbase = xb + (size_t)srow * HDIM + (size_t)skq * 8;

  float4 xa0, xa1, xb0, xb1;

#define LOADKC(kc)                                      \
  {                                                     \
    const float* bp = sbase + (kc) * BK;                \
    xa0 = ((const float4*)bp)[0];                       \
    xa1 = ((const float4*)bp)[1];                       \
    xb0 = ((const float4*)(bp + 64))[0];                \
    xb1 = ((const float4*)(bp + 64))[1];                \
  }

#define WRITEKC(kc)                                                    \
  {                                                                    \
    ushort8 pA, pB;                                                    \
    pA[0] = f2bf(xa0.x); pA[1] = f2bf(xa0.y); pA[2] = f2bf(xa0.z);     \
    pA[3] = f2bf(xa0.w); pA[4] = f2bf(xa1.x); pA[5] = f2bf(xa1.y);     \
    pA[6] = f2bf(xa1.z); pA[7] = f2bf(xa1.w);                          \
    pB[0] = f2bf(xb0.x); pB[1] = f2bf(xb0.y); pB[2] = f2bf(xb0.z);     \
    pB[3] = f2bf(xb0.w); pB[4] = f2bf(xb1.x); pB[5] = f2bf(xb1.y);     \
    pB[6] = f2bf(xb1.z); pB[7] = f2bf(xb1.w);                          \
    int base = srow * HDIM + (kc) * BK + slotA * 8;                    \
    *(ushort8*)&As[base] = pA;                                         \
    *(ushort8*)&As[base + 64] = pB;                                    \
  }

#define COMPUTEKC(kc)                                                          \
  {                                                                            \
    _Pragma("unroll")                                                          \
    for (int kk = 0; kk < 4; ++kk) {                                           \
      short8 afr[4], bfr[4];                                                   \
      int j = kk * 4 + q4;                                                     \
      _Pragma("unroll")                                                        \
      for (int m = 0; m < 4; ++m) {                                            \
        int row = wr * 64 + m * 16 + (l & 15);                                 \
        int P = (j & 8) | ((j & 7) ^ (row & 7));                               \
        afr[m] = *(const short8*)&As[row * HDIM + (kc) * BK + P * 8];          \
      }                                                                        \
      _Pragma("unroll")                                                        \
      for (int n = 0; n < 4; ++n) {                                            \
        int ct = wc * 4 + n, kt = (kc) * 4 + kk;                               \
        bfr[n] = *(const short8*)(uab + (((size_t)(ct * 16 + kt) * 64 + l) * 8)); \
      }                                                                        \
      __builtin_amdgcn_s_setprio(1);                                           \
      _Pragma("unroll")                                                        \
      for (int m = 0; m < 4; ++m)                                              \
        _Pragma("unroll")                                                      \
        for (int n = 0; n < 4; ++n)                                            \
          acc[m][n] = __builtin_amdgcn_mfma_f32_16x16x32_bf16(afr[m], bfr[n],  \
                                                              acc[m][n], 0, 0, 0); \
      __builtin_amdgcn_s_setprio(0);                                           \
    }                                                                          \
  }

  LOADKC(0);
  WRITEKC(0);
  __syncthreads();

  LOADKC(1);
  COMPUTEKC(0);
  WRITEKC(1);
  __syncthreads();

  LOADKC(2);
  COMPUTEKC(1);
  WRITEKC(2);
  __syncthreads();

  LOADKC(3);
  COMPUTEKC(2);
  WRITEKC(3);
  __syncthreads();

  // hoist q/Va loads under the last compute phase
  int c = l & 15, g4 = l >> 4;
  float qf[4], vf[4];
#pragma unroll
  for (int n = 0; n < 4; ++n) {
    int o = wc * 64 + n * 16 + c;
    qf[n] = q[b * HDIM + o];
    vf[n] = va[o];
  }
  COMPUTEKC(3);

  // scores[row] = sum_o tanh(acc + q[o]) * Va[o]; 8 col-group waves add per row
#pragma unroll
  for (int m = 0; m < 4; ++m) {
#pragma unroll
    for (int r = 0; r < 4; ++r) {
      float sum = 0.f;
#pragma unroll
      for (int n = 0; n < 4; ++n) sum += fast_tanh(acc[m][n][r] + qf[n]) * vf[n];
      sum += __shfl_xor(sum, 1);
      sum += __shfl_xor(sum, 2);
      sum += __shfl_xor(sum, 4);
      sum += __shfl_xor(sum, 8);
      if (c == 0) atomicAdd(&sc[wr * 64 + m * 16 + g4 * 4 + r], sum);
    }
  }
  __syncthreads();

  // softmax over the 128 local rows
  float sval = sc[tid & 127];
#pragma unroll
  for (int off = 32; off >= 1; off >>= 1) sval = fmaxf(sval, __shfl_xor(sval, off));
  if (l == 0) red1[w] = sval;
  __syncthreads();
  if (tid == 0) {
    float M = red1[0];
#pragma unroll
    for (int i = 1; i < 16; ++i) M = fmaxf(M, red1[i]);
    bc[0] = M;
  }
  __syncthreads();
  float M = bc[0];
  if (tid < BM) {
    float p = __expf(sc[tid] - M);
    pl[tid] = p;
    float lsum = p;
#pragma unroll
    for (int off = 32; off >= 1; off >>= 1) lsum += __shfl_xor(lsum, off);
    if (l == 0) red2[w] = lsum;
  }
  __syncthreads();
  if (tid == 0) {
    mArr[b * NCHUNK + chunk] = M;
    lArr[b * NCHUNK + chunk] = red2[0] + red2[1];
  }
  __syncthreads();

  // partial context from the bf16 LDS tile; two half-row groups + LDS combine
  {
    int half = tid >> 9;         // 0/1 -> rows 0..63 / 64..127
    int col = tid & 511;
    int kc_t = col >> 7;
    int j8 = (col >> 3) & 15;
    int e = col & 7;
    int base = kc_t * BK + (j8 & 8) * 8 + e;
    int jl = j8 & 7;
    float cacc = 0.f;
    int r0 = half * 64;
#pragma unroll 8
    for (int rr = 0; rr < 64; ++rr) {
      int r = r0 + rr;
      int P_low = jl ^ (r & 7);
      cacc += pl[r] * bf2f(As[r * HDIM + base + P_low * 8]);
    }
    if (half == 0) s_ctx[col] = cacc;
    __syncthreads();
    if (half == 1)
      cpart[((size_t)b * NCHUNK + chunk) * HDIM + col] = s_ctx[col] + cacc;
  }
#undef LOADKC
#undef WRITEKC
#undef COMPUTEKC
}

__global__ __launch_bounds__(512) void k_combine(const float* __restrict__ mArr,
                                                 const float* __restrict__ lArr,
                                                 const float* __restrict__ cpart,
                                                 float* __restrict__ ctx,
                                                 float* __restrict__ out_ctx) {
  int b = blockIdx.x, t = threadIdx.x;
  __shared__ float wf[NCHUNK];
  __shared__ float dinv;
  if (t == 0) {
    float M = mArr[b * NCHUNK];
    for (int i = 1; i < NCHUNK; ++i) M = fmaxf(M, mArr[b * NCHUNK + i]);
    float den = 0.f;
    for (int i = 0; i < NCHUNK; ++i) {
      float f = __expf(mArr[b * NCHUNK + i] - M);
      wf[i] = f;
      den += f * lArr[b * NCHUNK + i];
    }
    dinv = 1.0f / den;
  }
  __syncthreads();
  float s = 0.f;
#pragma unroll
  for (int i = 0; i < NCHUNK; ++i) s += wf[i] * cpart[((size_t)b * NCHUNK + i) * HDIM + t];
  float c = s * dinv;
  ctx[b * HDIM + t] = c;
  out_ctx[b * HDIM + t] = c;
}

__global__ __launch_bounds__(256) void k_rnn(const float* __restrict__ xt,
                                             const float* __restrict__ ctx,
                                             const float* __restrict__ hp,
                                             const float* __restrict__ Wih,
                                             const float* __restrict__ Wihb,
                                             const float* __restrict__ Whh,
                                             const float* __restrict__ Whhb,
                                             float* __restrict__ hout) {
  int b = blockIdx.x, oh = blockIdx.y;
  int o = oh * 256 + threadIdx.x;
  __shared__ float xs[EDIM], cs[HDIM], hs[HDIM];
  xs[threadIdx.x] = xt[b * EDIM + threadIdx.x];
  xs[threadIdx.x + 256] = xt[b * EDIM + threadIdx.x + 256];
  cs[threadIdx.x] = ctx[b * HDIM + threadIdx.x];
  cs[threadIdx.x + 256] = ctx[b * HDIM + threadIdx.x + 256];
  hs[threadIdx.x] = hp[b * HDIM + threadIdx.x];
  hs[threadIdx.x + 256] = hp[b * HDIM + threadIdx.x + 256];
  __syncthreads();
  const float4* wi = (const float4*)(Wih + (size_t)o * (EDIM + HDIM));
  float acc = Wihb[o] + Whhb[o];
#pragma unroll 8
  for (int i = 0; i < EDIM / 4; ++i) {
    float4 v = wi[i];
    acc += v.x * xs[i * 4] + v.y * xs[i * 4 + 1] + v.z * xs[i * 4 + 2] + v.w * xs[i * 4 + 3];
  }
  const float4* wi2 = wi + EDIM / 4;
#pragma unroll 8
  for (int i = 0; i < HDIM / 4; ++i) {
    float4 v = wi2[i];
    acc += v.x * cs[i * 4] + v.y * cs[i * 4 + 1] + v.z * cs[i * 4 + 2] + v.w * cs[i * 4 + 3];
  }
  const float4* wh = (const float4*)(Whh + (size_t)o * HDIM);
#pragma unroll 8
  for (int i = 0; i < HDIM / 4; ++i) {
    float4 v = wh[i];
    acc += v.x * hs[i * 4] + v.y * hs[i * 4 + 1] + v.z * hs[i * 4 + 2] + v.w * hs[i * 4 + 3];
  }
  hout[b * HDIM + o] = tanhf(acc);
}

extern "C" void kernel_launch(void* const* d_in, const int* in_sizes, int n_in,
                              void* d_out, int out_size, void* d_ws, size_t ws_size,
                              hipStream_t stream) {
  const float* x_t    = (const float*)d_in[0];
  const float* x_ref  = (const float*)d_in[1];
  const float* h_prev = (const float*)d_in[2];
  const float* Wa_w   = (const float*)d_in[3];
  const float* Wa_b   = (const float*)d_in[4];
  const float* Ua_w   = (const float*)d_in[5];
  const float* Ua_b   = (const float*)d_in[6];
  const float* Va_w   = (const float*)d_in[7];
  // d_in[8] = Va_b: softmax-invariant, skipped.
  const float* Wih_w  = (const float*)d_in[9];
  const float* Wih_b  = (const float*)d_in[10];
  const float* Whh_w  = (const float*)d_in[11];
  const float* Whh_b  = (const float*)d_in[12];

  char* ws = (char*)d_ws;
  unsigned short* ua_fr = (unsigned short*)ws;   // 512 KB fragment-layout Ua
  float* q     = (float*)(ws + 524288);          // 256 KB
  float* mArr  = (float*)(ws + 786432);          // 8 KB
  float* lArr  = (float*)(ws + 794624);          // 8 KB
  float* cpart = (float*)(ws + 802816);          // 4 MB
  float* ctx   = (float*)(ws + 4997120);         // 256 KB

  float* h_out   = (float*)d_out;
  float* ctx_out = h_out + BDIM * HDIM;

  k_cvt_b<<<dim3(128), dim3(256), 0, stream>>>(Ua_w, ua_fr);
  k_q<<<dim3(BDIM, 2), dim3(256), 0, stream>>>(h_prev, Wa_w, Wa_b, Ua_b, q);
  k_scores_ctx<<<dim3(NCHUNK, BDIM), dim3(1024), 0, stream>>>(x_ref, ua_fr, q, Va_w, mArr, lArr, cpart);
  k_combine<<<dim3(BDIM), dim3(512), 0, stream>>>(mArr, lArr, cpart, ctx, ctx_out);
  k_rnn<<<dim3(BDIM, 2), dim3(256), 0, stream>>>(x_t, ctx, h_prev, Wih_w, Wih_b, Whh_w, Whh_b, h_out);
}